// Round 3
// baseline (14862.186 us; speedup 1.0000x reference)
//
#include <hip/hip_runtime.h>
#include <hip/hip_bf16.h>

// LSTM decoder B=256, T=512, H=1024 — persistent-kernel split-bf16 MFMA.
// One kernel runs all 512 steps; 4 independent 64-WG m-group barriers per step
// (device-scope, handles cross-XCD L2 non-coherence via agent release/acquire).
// Per WG (m-group 64 rows x jt 16 h-cols x 4 gates):
//   W_hi slice (128 KB) persistent in LDS; W_lo streamed via 2x8KB LDS dbuf;
//   A (h hi/lo bf16) loaded global->fragment directly (no LDS);
//   acc nt-tiles == gates, epilogue fully in registers; c in registers for all steps.

#define BB 256
#define TT 512
#define HH 1024

typedef __attribute__((ext_vector_type(8))) short short8;
typedef __attribute__((ext_vector_type(4))) float float4v;

#define MFMA(a, b, c) __builtin_amdgcn_mfma_f32_16x16x32_bf16((a), (b), (c), 0, 0, 0)

#define WP_CPOFF ((size_t)4194304)      // shorts per W plane: 64jt*4g*32ks*64lane*8
#define HBUF ((size_t)BB * HH)          // 262144

__device__ __forceinline__ float sigf(float x) { return 1.0f / (1.0f + __expf(-x)); }
__device__ __forceinline__ float tanhff(float x) {
    return 1.0f - 2.0f / (__expf(2.0f * x) + 1.0f);
}
__device__ __forceinline__ unsigned short f2bf(float x) {
    __hip_bfloat16 b = __float2bfloat16(x);
    return __builtin_bit_cast(unsigned short, b);
}
__device__ __forceinline__ float bf2f(unsigned short u) {
    __hip_bfloat16 b = __builtin_bit_cast(__hip_bfloat16, u);
    return __bfloat162float(b);
}

// ---- pack W_hh (4096x1024 f32) into fragment-ordered bf16 hi/lo planes ----
// Wp[cp][jt(64)][g(4)][ks(32)][lane(64)][8] ; per-jt hi block = contiguous 128 KB
__global__ __launch_bounds__(256) void pack_w(const float* __restrict__ W_hh,
                                              unsigned short* __restrict__ Wp) {
    int gid = blockIdx.x * 256 + threadIdx.x;   // 0..524287
    int lane = gid & 63;
    int ks = (gid >> 6) & 31;
    int g = (gid >> 11) & 3;
    int jt = (gid >> 13) & 63;
    int r = g * HH + jt * 16 + (lane & 15);
    int k = ks * 32 + (lane >> 4) * 8;
    const float* src = W_hh + (size_t)r * HH + k;
    size_t base = ((((size_t)jt * 4 + g) * 32 + ks) * 64 + lane) * 8;
#pragma unroll
    for (int e = 0; e < 8; ++e) {
        float v = src[e];
        unsigned short hi = f2bf(v);
        Wp[base + e] = hi;
        Wp[WP_CPOFF + base + e] = f2bf(v - bf2f(hi));
    }
}

// ---- h0 -> bf16 hi/lo planes; zero barrier counters ----
__global__ __launch_bounds__(256) void prep_state(const float* __restrict__ h0,
                                                  unsigned short* __restrict__ hbuf,
                                                  unsigned int* __restrict__ cnt) {
    int i = blockIdx.x * 256 + threadIdx.x;
    if (i < BB * HH) {
        float v = h0[i];
        unsigned short hi = f2bf(v);
        hbuf[i] = hi;
        hbuf[HBUF + i] = f2bf(v - bf2f(hi));
    }
    if (blockIdx.x == 0 && threadIdx.x < 128) cnt[threadIdx.x] = 0;
}

// ---- persistent LSTM kernel: all 512 steps + final FC ----
__global__ __launch_bounds__(256, 1) void lstm_persist(
    const float* __restrict__ y_hist,
    const float* __restrict__ W_ih,           // (4096) flat = w_in
    const float* __restrict__ b_ih,
    const float* __restrict__ b_hh,
    const float* __restrict__ c0,             // (B,H) f32
    const float* __restrict__ W_fc,           // (H)
    const float* __restrict__ b_fc,           // (1)
    const unsigned short* __restrict__ Wp,    // packed hi/lo planes
    unsigned short* __restrict__ hb0,         // [2][B*H] hi,lo
    unsigned short* __restrict__ hb1,
    unsigned int* __restrict__ cnt,           // 4 groups x 32-uint padded lines
    float* __restrict__ out)
{
    __shared__ unsigned short Whi[65536];     // 128 KB, persistent W_hi slice
    __shared__ unsigned short Wls[2][4096];   // 2 x 8 KB W_lo chunk dbuf
    // total LDS = 144 KB -> exactly 1 WG/CU; grid=256 => all WGs co-resident

    const int tid = threadIdx.x;
    const int lane = tid & 63;
    const int wv = tid >> 6;                  // wave = m-subtile (16 rows)
    const int bid = blockIdx.x;
    const int jt = ((bid & 7) << 3) | ((bid >> 3) & 7);  // XCD-swizzled j-tile
    const int gm = bid >> 6;                  // m-group 0..3
    const int m0 = gm << 6;

    // --- load persistent W_hi slice into LDS (fragment order verbatim) ---
    const unsigned short* WhiG = Wp + (size_t)jt * 65536;
    for (int i = tid; i < 8192; i += 256)
        *(short8*)&Whi[(size_t)i * 8] = *(const short8*)(WhiG + (size_t)i * 8);

    // --- W_lo staging mapping: thread stages 32 B of the 8 KB chunk ---
    const int sf = tid >> 5;                  // 0..7 : frag (g, ksl)
    const int sg = sf >> 1, sksl = sf & 1;
    const int soff = (tid & 31) * 16;         // shorts within 512-short fragment
    const unsigned short* WloG = Wp + WP_CPOFF + (size_t)jt * 65536;

    // --- A fragment addressing (direct global->VGPR) ---
    const int ar = m0 + wv * 16 + (lane & 15);   // A row
    const int ak = (lane >> 4) * 8;              // k offset in 32-block

    // --- epilogue constants (fixed per thread across all steps) ---
    const int j = jt * 16 + (lane & 15);
    const int be = m0 + wv * 16 + (lane >> 4) * 4;   // epilogue row base
    float wi_[4], bs_[4];
#pragma unroll
    for (int g = 0; g < 4; ++g) {
        wi_[g] = W_ih[g * HH + j];
        bs_[g] = b_ih[g * HH + j] + b_hh[g * HH + j];
    }
    float c_[4];
#pragma unroll
    for (int r = 0; r < 4; ++r) c_[r] = c0[(size_t)(be + r) * HH + j];

    // prologue: stage W_lo chunk 0 into Wls[0]
    {
        const unsigned short* p = WloG + ((size_t)(sg * 32 + sksl) * 512) + soff;
        short8 w0 = *(const short8*)p;
        short8 w1 = *(const short8*)(p + 8);
        *(short8*)&Wls[0][(sg * 2 + sksl) * 512 + soff] = w0;
        *(short8*)&Wls[0][(sg * 2 + sksl) * 512 + soff + 8] = w1;
    }
    __syncthreads();   // Whi + Wls[0] visible

    unsigned int* mycnt = cnt + gm * 32;   // own 128B line per group

    for (int t = 0; t < TT; ++t) {
        const unsigned short* hs = (t & 1) ? hb1 : hb0;
        unsigned short* hd = (t & 1) ? hb0 : hb1;

        float x_[4];
#pragma unroll
        for (int r = 0; r < 4; ++r) x_[r] = y_hist[(size_t)(be + r) * TT + t];

        float4v acc[4] = {{0.f, 0.f, 0.f, 0.f}, {0.f, 0.f, 0.f, 0.f},
                          {0.f, 0.f, 0.f, 0.f}, {0.f, 0.f, 0.f, 0.f}};
        const unsigned short* abase = hs + (size_t)ar * HH + ak;
        short8 a_cur[2][2], a_nxt[2][2];   // [cp][ksl]
#pragma unroll
        for (int cp = 0; cp < 2; ++cp)
#pragma unroll
            for (int ksl = 0; ksl < 2; ++ksl)
                a_cur[cp][ksl] = *(const short8*)(abase + (size_t)cp * HBUF + ksl * 32);

        for (int ch = 0; ch < 16; ++ch) {
            const int cur = ch & 1;
            if (ch < 15) {
#pragma unroll
                for (int cp = 0; cp < 2; ++cp)
#pragma unroll
                    for (int ksl = 0; ksl < 2; ++ksl)
                        a_nxt[cp][ksl] = *(const short8*)(abase + (size_t)cp * HBUF +
                                                          (ch + 1) * 64 + ksl * 32);
            }
            const int nc = (ch + 1) & 15;    // W_lo wraps to chunk 0 for next step
            const unsigned short* p = WloG + ((size_t)(sg * 32 + nc * 2 + sksl) * 512) + soff;
            short8 w0 = *(const short8*)p;
            short8 w1 = *(const short8*)(p + 8);

#pragma unroll
            for (int ksl = 0; ksl < 2; ++ksl) {
#pragma unroll
                for (int g = 0; g < 4; ++g) {
                    short8 bh = *(const short8*)&Whi[((g * 32 + ch * 2 + ksl) * 64 + lane) * 8];
                    short8 bl = *(const short8*)&Wls[cur][((g * 2 + ksl) * 64 + lane) * 8];
                    acc[g] = MFMA(a_cur[1][ksl], bh, acc[g]);   // A_lo * W_hi
                    acc[g] = MFMA(a_cur[0][ksl], bl, acc[g]);   // A_hi * W_lo
                    acc[g] = MFMA(a_cur[0][ksl], bh, acc[g]);   // A_hi * W_hi
                }
            }
            *(short8*)&Wls[1 - cur][(sg * 2 + sksl) * 512 + soff] = w0;
            *(short8*)&Wls[1 - cur][(sg * 2 + sksl) * 512 + soff + 8] = w1;
            __syncthreads();
            if (ch < 15) {
#pragma unroll
                for (int cp = 0; cp < 2; ++cp)
#pragma unroll
                    for (int ksl = 0; ksl < 2; ++ksl)
                        a_cur[cp][ksl] = a_nxt[cp][ksl];
            }
        }

        // --- epilogue: acc[g][r] is gate g at (row be+r, col j) — all registers
#pragma unroll
        for (int r = 0; r < 4; ++r) {
            float gi = acc[0][r] + x_[r] * wi_[0] + bs_[0];
            float gf = acc[1][r] + x_[r] * wi_[1] + bs_[1];
            float gg = acc[2][r] + x_[r] * wi_[2] + bs_[2];
            float go = acc[3][r] + x_[r] * wi_[3] + bs_[3];
            float cn = sigf(gf) * c_[r] + sigf(gi) * tanhff(gg);
            float hn = sigf(go) * tanhff(cn);
            c_[r] = cn;
            unsigned short hi_ = f2bf(hn);
            hd[(size_t)(be + r) * HH + j] = hi_;
            hd[HBUF + (size_t)(be + r) * HH + j] = f2bf(hn - bf2f(hi_));
        }

        // --- m-group barrier (64 WGs, device scope, monotonic count) ---
        __syncthreads();
        if (tid == 0) {
            __threadfence();
            __hip_atomic_fetch_add(mycnt, 1u, __ATOMIC_RELEASE, __HIP_MEMORY_SCOPE_AGENT);
            unsigned target = 64u * (unsigned)(t + 1);
            while (__hip_atomic_load(mycnt, __ATOMIC_RELAXED, __HIP_MEMORY_SCOPE_AGENT) < target)
                __builtin_amdgcn_s_sleep(2);
            __threadfence();
        }
        __syncthreads();
    }

    // --- inlined FC: out[b] = sum_k (h_hi+h_lo)[b][k] * W_fc[k] + b_fc ---
    // final h (t=511) landed in hb0; jt==0 WG of each m-group handles its 64 rows
    if (jt == 0) {
#pragma unroll 1
        for (int rr = 0; rr < 16; ++rr) {
            int b = m0 + wv * 16 + rr;
            float s = 0.f;
            for (int k = lane; k < HH; k += 64)
                s += (bf2f(hb0[(size_t)b * HH + k]) + bf2f(hb0[HBUF + (size_t)b * HH + k])) *
                     W_fc[k];
#pragma unroll
            for (int off = 32; off > 0; off >>= 1) s += __shfl_xor(s, off);
            if (lane == 0) out[b] = s + b_fc[0];
        }
    }
}

extern "C" void kernel_launch(void* const* d_in, const int* in_sizes, int n_in,
                              void* d_out, int out_size, void* d_ws, size_t ws_size,
                              hipStream_t stream) {
    const float* y_hist = (const float*)d_in[0];
    const float* W_ih   = (const float*)d_in[1];
    const float* W_hh   = (const float*)d_in[2];
    const float* b_ih   = (const float*)d_in[3];
    const float* b_hh   = (const float*)d_in[4];
    const float* W_fc   = (const float*)d_in[5];
    const float* b_fc   = (const float*)d_in[6];
    const float* h0     = (const float*)d_in[7];
    const float* c0     = (const float*)d_in[8];
    float* out = (float*)d_out;

    // ws: Wp hi/lo (16 MB) | hb0 (1 MB) | hb1 (1 MB) | cnt (512 B)
    unsigned short* Wp = (unsigned short*)d_ws;
    unsigned short* hb0 = Wp + 2 * WP_CPOFF;
    unsigned short* hb1 = hb0 + 2 * HBUF;
    unsigned int* cnt = (unsigned int*)(hb1 + 2 * HBUF);

    pack_w<<<2048, 256, 0, stream>>>(W_hh, Wp);
    prep_state<<<(BB * HH + 255) / 256, 256, 0, stream>>>(h0, hb0, cnt);

    // 256 WGs, 144 KB LDS each -> exactly 1 WG/CU on 256 CUs: all co-resident.
    lstm_persist<<<256, 256, 0, stream>>>(y_hist, W_ih, b_ih, b_hh, c0, W_fc, b_fc,
                                          Wp, hb0, hb1, cnt, out);
}

// Round 4
// 5497.940 us; speedup vs baseline: 2.7032x; 2.7032x over previous
//
#include <hip/hip_runtime.h>
#include <hip/hip_bf16.h>

// LSTM decoder B=256, T=512, H=1024 — persistent split-bf16 MFMA, v2.
// Key changes vs v1-persistent:
//  * NO cache-maintenance fences: all cross-WG data (h, counters) uses
//    agent-scope RELAXED atomics (per-access L2 bypass). Ordering: __syncthreads
//    drains vmcnt(0) before tid0's counter add (compiler-guaranteed drain).
//  * h stored packed (hi|lo per uint32) in MFMA-fragment-shuffled layout with
//    [pair][lane] interleave -> A loads are lane-consecutive b64 (perfect coalesce).
//  * 512 threads = 8 waves (2/SIMD): waves = (wv_m 0..3) x (wv_k 0..1) K-split,
//    partials reduced through LDS at step end.
//  * LDS: W_hi 128 KB persistent + W_lo 2x16 KB dbuf = 160 KiB exactly.

#define BB 256
#define TT 512
#define HH 1024

typedef __attribute__((ext_vector_type(8))) short short8;
typedef __attribute__((ext_vector_type(4))) float float4v;

#define MFMA(a, b, c) __builtin_amdgcn_mfma_f32_16x16x32_bf16((a), (b), (c), 0, 0, 0)

#define WP_CPOFF ((size_t)4194304)   // shorts per W plane: 64jt*4g*32ks*64lane*8
#define HP_U64   ((size_t)131072)    // u64 per h buffer: 16blk*32ks*4p*64lane

__device__ __forceinline__ float sigf(float x) { return 1.0f / (1.0f + __expf(-x)); }
__device__ __forceinline__ float tanhff(float x) {
    return 1.0f - 2.0f / (__expf(2.0f * x) + 1.0f);
}
__device__ __forceinline__ unsigned short f2bf(float x) {
    __hip_bfloat16 b = __float2bfloat16(x);
    return __builtin_bit_cast(unsigned short, b);
}
__device__ __forceinline__ float bf2f(unsigned short u) {
    __hip_bfloat16 b = __builtin_bit_cast(__hip_bfloat16, u);
    return __bfloat162float(b);
}

// ---- pack W_hh (4096x1024 f32) into fragment-ordered bf16 hi/lo planes ----
// Wp[cp][jt(64)][g(4)][ks(32)][lane(64)][8]
__global__ __launch_bounds__(256) void pack_w(const float* __restrict__ W_hh,
                                              unsigned short* __restrict__ Wp) {
    int gid = blockIdx.x * 256 + threadIdx.x;   // 0..524287
    int lane = gid & 63;
    int ks = (gid >> 6) & 31;
    int g = (gid >> 11) & 3;
    int jt = (gid >> 13) & 63;
    int r = g * HH + jt * 16 + (lane & 15);
    int k = ks * 32 + (lane >> 4) * 8;
    const float* src = W_hh + (size_t)r * HH + k;
    size_t base = ((((size_t)jt * 4 + g) * 32 + ks) * 64 + lane) * 8;
#pragma unroll
    for (int e = 0; e < 8; ++e) {
        float v = src[e];
        unsigned short hi = f2bf(v);
        Wp[base + e] = hi;
        Wp[WP_CPOFF + base + e] = f2bf(v - bf2f(hi));
    }
}

// ---- h0 -> packed fragment layout in buffer 0; zero barrier counters ----
// element (r,k): word = hi | lo<<16 at u32 idx = (((blk*32+ks)*4+p)*64 + l)*2 + half
// blk = (r>>6)*4 + ((r>>4)&3), ks = k>>5, p = (k&7)>>1, half = k&1,
// l = (r&15) + 16*((k&31)>>3)
__global__ __launch_bounds__(256) void prep_state(const float* __restrict__ h0,
                                                  unsigned int* __restrict__ hb0,
                                                  unsigned int* __restrict__ cnt) {
    int gid = blockIdx.x * 256 + threadIdx.x;   // 0..262143
    int r = gid >> 10, k = gid & 1023;
    float v = h0[gid];
    unsigned short hi = f2bf(v);
    unsigned short lo = f2bf(v - bf2f(hi));
    unsigned int word = (unsigned int)hi | ((unsigned int)lo << 16);
    int blk = ((r >> 6) << 2) | ((r >> 4) & 3);
    int l = (r & 15) + (((k & 31) >> 3) << 4);
    size_t idx64 = (((size_t)blk * 32 + (k >> 5)) * 4 + ((k & 7) >> 1)) * 64 + l;
    hb0[idx64 * 2 + (k & 1)] = word;
    if (blockIdx.x == 0 && threadIdx.x < 128) cnt[threadIdx.x] = 0;
}

// ---- persistent LSTM kernel: all 512 steps + final FC ----
__global__ __launch_bounds__(512, 1) void lstm_persist(
    const float* __restrict__ y_hist,
    const float* __restrict__ W_ih,           // (4096) flat
    const float* __restrict__ b_ih,
    const float* __restrict__ b_hh,
    const float* __restrict__ c0,             // (B,H) f32
    const float* __restrict__ W_fc,           // (H)
    const float* __restrict__ b_fc,           // (1)
    const unsigned short* __restrict__ Wp,    // packed hi/lo planes
    unsigned long long* __restrict__ hbase,   // 2 buffers x HP_U64 u64
    unsigned int* __restrict__ cnt,
    float* __restrict__ out)
{
    __shared__ unsigned short Whi[65536];      // 128 KB persistent W_hi slice
    __shared__ __align__(16) unsigned short Wls[2][8192];  // 2 x 16 KB W_lo dbuf
    // 160 KiB exactly -> 1 WG/CU, grid=256 => all WGs co-resident

    const int tid = threadIdx.x;
    const int lane = tid & 63;
    const int wv = tid >> 6;
    const int wv_m = wv & 3;                   // m-subtile (16 rows)
    const int wv_k = wv >> 2;                  // K half
    const int bid = blockIdx.x;
    const int jt = ((bid & 7) << 3) | ((bid >> 3) & 7);  // XCD-swizzled j-tile
    const int gm = bid >> 6;                   // m-group 0..3
    const int m0 = gm << 6;

    // --- persistent W_hi slice -> LDS (coalesced b128) ---
    const unsigned short* WhiG = Wp + (size_t)jt * 65536;
    for (int i = tid; i < 8192; i += 512)
        *(short8*)&Whi[(size_t)i * 8] = *(const short8*)(WhiG + (size_t)i * 8);

    // --- W_lo staging mapping: thread stages 32 B of a 16 KB iter-chunk ---
    const int sf = tid >> 5;                   // 0..15 : (wk2, g2, ksl2)
    const int swk = sf >> 3, sg = (sf >> 1) & 3, sksl = sf & 1;
    const int soff = (tid & 31) * 16;          // shorts
    const unsigned short* WloG = Wp + WP_CPOFF + (size_t)jt * 65536;

    // --- A addressing: u64 block base for (gm, wv_m) ---
    const size_t ablk = ((size_t)(gm * 4 + wv_m) * 32) * 256;  // + ks*256 + p*64 + lane

    // --- epilogue constants (wv_k==0 threads only use these) ---
    const int j = jt * 16 + (lane & 15);
    const int be = m0 + wv_m * 16 + (lane >> 4) * 4;
    float wi_[4], bs_[4];
#pragma unroll
    for (int g = 0; g < 4; ++g) {
        wi_[g] = W_ih[g * HH + j];
        bs_[g] = b_ih[g * HH + j] + b_hh[g * HH + j];
    }
    float c_[4];
#pragma unroll
    for (int r = 0; r < 4; ++r) c_[r] = c0[(size_t)(be + r) * HH + j];
    // h-store base (u64 index, lane's column j, rows be..be+3)
    const int ksj = j >> 5, pj = (j & 7) >> 1, hfj = j & 1;
    const size_t sblk = (((size_t)(gm * 4 + wv_m) * 32 + ksj) * 4 + pj) * 64 +
                        (((j & 31) >> 3) << 4) + ((lane >> 4) << 2);

    // prologue: stage W_lo iter 0 into buf 0
    {
        const unsigned short* src = WloG + ((sg * 32 + swk * 16 + 0 + sksl) * 512) + soff;
        short8 v0 = *(const short8*)src;
        short8 v1 = *(const short8*)(src + 8);
        unsigned short* dp = &Wls[0][(((swk * 4 + sg) * 2 + sksl) * 512) + soff];
        *(short8*)dp = v0;
        *(short8*)(dp + 8) = v1;
    }
    __syncthreads();

    unsigned int* mycnt = cnt + gm * 32;
    float* scr = (float*)&Wls[1][0];           // 16 KB reduction scratch (reused)

    union U8 { short8 s8; unsigned int u[4]; };

    for (int t = 0; t < TT; ++t) {
        const unsigned long long* hR = hbase + (size_t)(t & 1) * HP_U64;
        unsigned int* hW32 = (unsigned int*)(hbase + (size_t)((t + 1) & 1) * HP_U64);

        float4v acc[4] = {{0.f, 0.f, 0.f, 0.f}, {0.f, 0.f, 0.f, 0.f},
                          {0.f, 0.f, 0.f, 0.f}, {0.f, 0.f, 0.f, 0.f}};
        unsigned long long au_cur[2][4], au_nxt[2][4];

        // A prologue: chunk 0 (ks = wv_k*16 + ksl)
#pragma unroll
        for (int ksl = 0; ksl < 2; ++ksl) {
            int ks = wv_k * 16 + ksl;
#pragma unroll
            for (int p = 0; p < 4; ++p)
                au_cur[ksl][p] = __hip_atomic_load(
                    (unsigned long long*)&hR[ablk + (size_t)ks * 256 + p * 64 + lane],
                    __ATOMIC_RELAXED, __HIP_MEMORY_SCOPE_AGENT);
        }

        for (int i = 0; i < 8; ++i) {
            if (i < 7) {
#pragma unroll
                for (int ksl = 0; ksl < 2; ++ksl) {
                    int ks = wv_k * 16 + (i + 1) * 2 + ksl;
#pragma unroll
                    for (int p = 0; p < 4; ++p)
                        au_nxt[ksl][p] = __hip_atomic_load(
                            (unsigned long long*)&hR[ablk + (size_t)ks * 256 + p * 64 + lane],
                            __ATOMIC_RELAXED, __HIP_MEMORY_SCOPE_AGENT);
                }
            }
            // stage W_lo iter (i+1)&7 into buf (i+1)&1 (at i=7: iter0->buf0 for next step)
            {
                const int it = (i + 1) & 7;
                const unsigned short* src =
                    WloG + ((sg * 32 + swk * 16 + it * 2 + sksl) * 512) + soff;
                short8 v0 = *(const short8*)src;
                short8 v1 = *(const short8*)(src + 8);
                unsigned short* dp =
                    &Wls[(i + 1) & 1][(((swk * 4 + sg) * 2 + sksl) * 512) + soff];
                *(short8*)dp = v0;
                *(short8*)(dp + 8) = v1;
            }
            // compute on au_cur + Wls[i&1]
#pragma unroll
            for (int ksl = 0; ksl < 2; ++ksl) {
                const int ks = wv_k * 16 + i * 2 + ksl;
                U8 ah, al;
#pragma unroll
                for (int d = 0; d < 4; ++d) {
                    unsigned int w0 = (unsigned int)au_cur[ksl][d];
                    unsigned int w1 = (unsigned int)(au_cur[ksl][d] >> 32);
                    ah.u[d] = (w0 & 0xFFFFu) | (w1 << 16);
                    al.u[d] = (w0 >> 16) | (w1 & 0xFFFF0000u);
                }
#pragma unroll
                for (int g = 0; g < 4; ++g) {
                    short8 bh = *(const short8*)&Whi[((g * 32 + ks) * 64 + lane) * 8];
                    short8 bl = *(const short8*)
                        &Wls[i & 1][(((wv_k * 4 + g) * 2 + ksl) * 64 + lane) * 8];
                    acc[g] = MFMA(ah.s8, bh, acc[g]);   // A_hi * W_hi
                    acc[g] = MFMA(ah.s8, bl, acc[g]);   // A_hi * W_lo
                    acc[g] = MFMA(al.s8, bh, acc[g]);   // A_lo * W_hi
                }
            }
            __syncthreads();
#pragma unroll
            for (int ksl = 0; ksl < 2; ++ksl)
#pragma unroll
                for (int p = 0; p < 4; ++p) au_cur[ksl][p] = au_nxt[ksl][p];
        }

        // --- cross-wv_k reduction through LDS scratch (Wls[1] region) ---
        if (wv_k == 1) {
            const int tid2 = tid - 256;
#pragma unroll
            for (int g = 0; g < 4; ++g)
                *(float4v*)&scr[(g * 256 + tid2) * 4] = acc[g];
        }
        __syncthreads();

        if (wv_k == 0) {
#pragma unroll
            for (int g = 0; g < 4; ++g) {
                float4v part = *(const float4v*)&scr[(g * 256 + tid) * 4];
                acc[g] += part;
            }
            // --- epilogue: gates -> c,h update; packed atomic h stores ---
#pragma unroll
            for (int r = 0; r < 4; ++r) {
                float x = y_hist[(size_t)(be + r) * TT + t];
                float gi = acc[0][r] + x * wi_[0] + bs_[0];
                float gf = acc[1][r] + x * wi_[1] + bs_[1];
                float gg = acc[2][r] + x * wi_[2] + bs_[2];
                float go = acc[3][r] + x * wi_[3] + bs_[3];
                float cn = sigf(gf) * c_[r] + sigf(gi) * tanhff(gg);
                float hn = sigf(go) * tanhff(cn);
                c_[r] = cn;
                unsigned short hi = f2bf(hn);
                unsigned short lo = f2bf(hn - bf2f(hi));
                unsigned int word = (unsigned int)hi | ((unsigned int)lo << 16);
                __hip_atomic_store(&hW32[(sblk + r) * 2 + hfj], word,
                                   __ATOMIC_RELAXED, __HIP_MEMORY_SCOPE_AGENT);
            }
        }

        // --- m-group barrier: syncthreads drains all stores (vmcnt 0), then count
        __syncthreads();
        if (tid == 0) {
            __hip_atomic_fetch_add(mycnt, 1u, __ATOMIC_RELAXED, __HIP_MEMORY_SCOPE_AGENT);
            unsigned target = 64u * (unsigned)(t + 1);
            while (__hip_atomic_load(mycnt, __ATOMIC_RELAXED, __HIP_MEMORY_SCOPE_AGENT) <
                   target)
                __builtin_amdgcn_s_sleep(1);
        }
        __syncthreads();
    }

    // --- final FC (h final in buffer 0): jt==0 WGs, wv_k==0 waves ---
    if (jt == 0 && wv_k == 0) {
        const unsigned int* hF32 = (const unsigned int*)hbase;   // buffer 0
#pragma unroll 1
        for (int rr = 0; rr < 16; ++rr) {
            int b = m0 + wv_m * 16 + rr;
            float s = 0.f;
#pragma unroll 1
            for (int ii = 0; ii < 16; ++ii) {
                int k = ii * 64 + lane;
                int l = (rr & 15) + (((k & 31) >> 3) << 4);
                size_t idx64 = (((size_t)(gm * 4 + wv_m) * 32 + (k >> 5)) * 4 +
                                ((k & 7) >> 1)) * 64 + l;
                unsigned int word = __hip_atomic_load(
                    (unsigned int*)&hF32[idx64 * 2 + (k & 1)],
                    __ATOMIC_RELAXED, __HIP_MEMORY_SCOPE_AGENT);
                float hv = bf2f((unsigned short)(word & 0xFFFFu)) +
                           bf2f((unsigned short)(word >> 16));
                s = fmaf(hv, W_fc[k], s);
            }
#pragma unroll
            for (int off = 32; off > 0; off >>= 1) s += __shfl_xor(s, off);
            if (lane == 0) out[b] = s + b_fc[0];
        }
    }
}

extern "C" void kernel_launch(void* const* d_in, const int* in_sizes, int n_in,
                              void* d_out, int out_size, void* d_ws, size_t ws_size,
                              hipStream_t stream) {
    const float* y_hist = (const float*)d_in[0];
    const float* W_ih   = (const float*)d_in[1];
    const float* W_hh   = (const float*)d_in[2];
    const float* b_ih   = (const float*)d_in[3];
    const float* b_hh   = (const float*)d_in[4];
    const float* W_fc   = (const float*)d_in[5];
    const float* b_fc   = (const float*)d_in[6];
    const float* h0     = (const float*)d_in[7];
    const float* c0     = (const float*)d_in[8];
    float* out = (float*)d_out;

    // ws: Wp hi/lo (16 MB) | h buffers 2 x 1 MB | cnt (512 B)
    unsigned short* Wp = (unsigned short*)d_ws;
    unsigned long long* hbase = (unsigned long long*)(Wp + 2 * WP_CPOFF);
    unsigned int* cnt = (unsigned int*)(hbase + 2 * HP_U64);

    pack_w<<<2048, 256, 0, stream>>>(W_hh, Wp);
    prep_state<<<1024, 256, 0, stream>>>(h0, (unsigned int*)hbase, cnt);

    // 256 WGs x 512 threads, 160 KiB LDS -> 1 WG/CU, all co-resident
    lstm_persist<<<256, 512, 0, stream>>>(y_hist, W_ih, b_ih, b_hh, c0, W_fc, b_fc,
                                          Wp, hbase, cnt, out);
}